// Round 3
// baseline (241.901 us; speedup 1.0000x reference)
//
#include <hip/hip_runtime.h>

// out[i] = g(data[i]) where g = (x*MAXVAL*ct) -> 3 Hermite-spline ODE steps -> (*st/MAXVAL).
// g is piecewise-smooth on [0,4] (post-ct space) and exactly affine outside.
// Pre-kernel tabulates g at 1024 knots over [-0.5, 4.5] into d_ws; main kernel
// does a fused lerp lookup from LDS. Memory-bound; R1 fix: explicit 8-deep MLP
// (all global loads issued before any LDS use) + nontemporal stores.
// R2: use native ext_vector_type for __builtin_nontemporal_store (HIP float4
// is a class type the builtin rejects).

#define MAXVAL_F 1.1752011936438014f

typedef float nfloat4 __attribute__((ext_vector_type(4)));  // native vec for nt-store

constexpr int   TAB_N  = 1024;
constexpr float TAB_L0 = -0.5f;
constexpr float TAB_H  = 5.0f / (float)TAB_N;   // covers [-0.5, 4.5]
constexpr int   ITER   = 8;                     // float4 per thread
constexpr int   BLK    = 256;
constexpr int   F4_PER_BLOCK = BLK * ITER;      // 2048

// Exact reference-faithful evaluation of the 3-step map in post-ct space
// (excluding the final st/MAXVAL scale).
__device__ __forceinline__ float eval_exact(float x,
    const float* __restrict__ vt, const float* __restrict__ at) {
#pragma unroll
  for (int k = 0; k < 3; ++k) {
    float t = fminf(fmaxf(x, 0.0f), 4.0f);   // clip(x, 0, NUM_POINTS-1)
    int i0 = (int)t;                          // t >= 0 so trunc == floor
    if (i0 > 3) i0 = 3;                       // clip to NUM_POINTS-2
    float u  = t - (float)i0;
    float u2 = u * u, u3 = u2 * u;
    float h00 =  2.0f * u3 - 3.0f * u2 + 1.0f;
    float h10 =         u3 - 2.0f * u2 + u;
    float h01 = -2.0f * u3 + 3.0f * u2;
    float h11 =         u3 -        u2;
    // table layout: row 0 = values [0..4], row 1 = tangents [5..9]
    float vel = h00 * vt[i0] + h10 * vt[5 + i0] + h01 * vt[i0 + 1] + h11 * vt[6 + i0];
    float ang = h00 * at[i0] + h10 * at[5 + i0] + h01 * at[i0 + 1] + h11 * at[6 + i0];
    float sn = sinf(ang);
    float cs = cosf(ang);
    x = x + (vel * cs + x * vel * sn) * (1.0f / 3.0f);
  }
  return x;
}

// Tiny launch: each thread computes g at its knot and the next knot (exactly),
// stores (g_j, g_{j+1}-g_j) for single-FMA lerp in the main kernel.
__global__ void build_table_kernel(const float* __restrict__ vt,
                                   const float* __restrict__ at,
                                   const float* __restrict__ stp,
                                   float2* __restrict__ gtab) {
  int j = blockIdx.x * blockDim.x + threadIdx.x;
  if (j >= TAB_N) return;
  float sc = stp[0] * (1.0f / MAXVAL_F);
  float x0 = TAB_L0 + TAB_H * (float)j;
  float x1 = TAB_L0 + TAB_H * (float)(j + 1);
  float g0 = eval_exact(x0, vt, at) * sc;
  float g1 = eval_exact(x1, vt, at) * sc;
  gtab[j] = make_float2(g0, g1 - g0);
}

__device__ __forceinline__ float lerp_tab(float x, float C1, float C0,
                                          const float2* __restrict__ tab) {
  float s  = fmaf(x, C1, C0);
  float fj = floorf(s);
  fj = fminf(fmaxf(fj, 0.0f), (float)(TAB_N - 2));
  float u  = s - fj;                 // may be <0 or >1: exact affine extrapolation
  float2 e = tab[(int)fj];
  return fmaf(u, e.y, e.x);
}

__device__ __forceinline__ void nt_store4(float4 o, float4* p) {
  nfloat4 v = {o.x, o.y, o.z, o.w};
  __builtin_nontemporal_store(v, (nfloat4*)p);
}

// Main kernel: 8 float4 loads issued back-to-back (8-deep MLP), then 32 LDS
// lerp lookups, then 8 nontemporal float4 stores. No per-element bounds check
// except in the (normally absent) ragged tail block.
__global__ __launch_bounds__(BLK) void apply_map_kernel(
    const float4* __restrict__ in, float4* __restrict__ out,
    const float2* __restrict__ gtab, const float* __restrict__ ctp, int nf4) {
  __shared__ float2 tab[TAB_N];
  {
    const float4* g4 = (const float4*)gtab;
    float4* t4 = (float4*)tab;
#pragma unroll
    for (int i = 0; i < 2; ++i)
      t4[(int)threadIdx.x + i * BLK] = g4[(int)threadIdx.x + i * BLK];
  }
  float C1 = ctp[0] * (MAXVAL_F / TAB_H);   // s = data*C1 + C0
  const float C0 = -TAB_L0 / TAB_H;
  __syncthreads();

  int base = (int)blockIdx.x * F4_PER_BLOCK + (int)threadIdx.x;

  if (base + (ITER - 1) * BLK < nf4) {      // full block: unchecked fast path
    float4 d[ITER];
#pragma unroll
    for (int k = 0; k < ITER; ++k) d[k] = in[base + k * BLK];   // 8 loads in flight
#pragma unroll
    for (int k = 0; k < ITER; ++k) {
      float4 o;
      o.x = lerp_tab(d[k].x, C1, C0, tab);
      o.y = lerp_tab(d[k].y, C1, C0, tab);
      o.z = lerp_tab(d[k].z, C1, C0, tab);
      o.w = lerp_tab(d[k].w, C1, C0, tab);
      nt_store4(o, &out[base + k * BLK]);
    }
  } else {                                   // ragged tail (unused at N=2^25)
#pragma unroll
    for (int k = 0; k < ITER; ++k) {
      int idx = base + k * BLK;
      if (idx < nf4) {
        float4 d = in[idx];
        float4 o;
        o.x = lerp_tab(d.x, C1, C0, tab);
        o.y = lerp_tab(d.y, C1, C0, tab);
        o.z = lerp_tab(d.z, C1, C0, tab);
        o.w = lerp_tab(d.w, C1, C0, tab);
        nt_store4(o, &out[idx]);
      }
    }
  }
}

extern "C" void kernel_launch(void* const* d_in, const int* in_sizes, int n_in,
                              void* d_out, int out_size, void* d_ws, size_t ws_size,
                              hipStream_t stream) {
  const float* data = (const float*)d_in[0];
  const float* vel  = (const float*)d_in[1];
  const float* ang  = (const float*)d_in[2];
  const float* ct   = (const float*)d_in[3];
  const float* st   = (const float*)d_in[4];
  float*       outp = (float*)d_out;
  float2*      gtab = (float2*)d_ws;   // 1024 * 8 B = 8 KiB scratch

  hipLaunchKernelGGL(build_table_kernel, dim3((TAB_N + 255) / 256), dim3(256), 0, stream,
                     vel, ang, st, gtab);

  int n   = in_sizes[0];          // 33,554,432
  int nf4 = n / 4;                // 8,388,608 = 4096 * 2048 exactly
  int blocks = (nf4 + F4_PER_BLOCK - 1) / F4_PER_BLOCK;
  hipLaunchKernelGGL(apply_map_kernel, dim3(blocks), dim3(BLK), 0, stream,
                     (const float4*)data, (float4*)outp, gtab, ct, nf4);
}

// Round 4
// 240.976 us; speedup vs baseline: 1.0038x; 1.0038x over previous
//
#include <hip/hip_runtime.h>

// out[i] = g(data[i]) where g = (x*MAXVAL*ct) -> 3 Hermite-spline ODE steps -> (*st/MAXVAL).
// g is piecewise-smooth on [0,4] (post-ct space) and exactly affine outside.
// Pre-kernel tabulates g (value-only) at 512 knots over [-0.5, 4.5] into d_ws.
// R3: bank-private LDS table — 16 replicas so lane l reads replica l&15:
// max 2 lanes/bank per phase (free, m136). Slope computed as a1-a0 on the fly.
// R0/R2 identical 80us at identical conflict counts => scatter ds_read_b64 was
// serializing the LDS pipe; this layout makes every LDS read ~conflict-free.

#define MAXVAL_F 1.1752011936438014f

typedef float nfloat4 __attribute__((ext_vector_type(4)));  // native vec for nt-store

constexpr int   TAB_K  = 512;                    // knots
constexpr int   REP    = 16;                     // lane replicas (lane & 15)
constexpr float TAB_L0 = -0.5f;
constexpr float TAB_HI = 4.5f;
constexpr float INV_H  = (float)(TAB_K - 1) / (TAB_HI - TAB_L0);  // 511/5
constexpr int   ITER   = 8;                      // float4 per thread
constexpr int   BLK    = 256;
constexpr int   F4_PER_BLOCK = BLK * ITER;       // 2048

// Exact reference-faithful evaluation of the 3-step map in post-ct space
// (excluding the final st/MAXVAL scale).
__device__ __forceinline__ float eval_exact(float x,
    const float* __restrict__ vt, const float* __restrict__ at) {
#pragma unroll
  for (int k = 0; k < 3; ++k) {
    float t = fminf(fmaxf(x, 0.0f), 4.0f);   // clip(x, 0, NUM_POINTS-1)
    int i0 = (int)t;                          // t >= 0 so trunc == floor
    if (i0 > 3) i0 = 3;                       // clip to NUM_POINTS-2
    float u  = t - (float)i0;
    float u2 = u * u, u3 = u2 * u;
    float h00 =  2.0f * u3 - 3.0f * u2 + 1.0f;
    float h10 =         u3 - 2.0f * u2 + u;
    float h01 = -2.0f * u3 + 3.0f * u2;
    float h11 =         u3 -        u2;
    // table layout: row 0 = values [0..4], row 1 = tangents [5..9]
    float vel = h00 * vt[i0] + h10 * vt[5 + i0] + h01 * vt[i0 + 1] + h11 * vt[6 + i0];
    float ang = h00 * at[i0] + h10 * at[5 + i0] + h01 * at[i0 + 1] + h11 * at[6 + i0];
    float sn = sinf(ang);
    float cs = cosf(ang);
    x = x + (vel * cs + x * vel * sn) * (1.0f / 3.0f);
  }
  return x;
}

// Tiny launch: knot values of the composed map, fully scaled.
__global__ void build_table_kernel(const float* __restrict__ vt,
                                   const float* __restrict__ at,
                                   const float* __restrict__ stp,
                                   float* __restrict__ gtab) {
  int j = blockIdx.x * blockDim.x + threadIdx.x;
  if (j >= TAB_K) return;
  float sc = stp[0] * (1.0f / MAXVAL_F);
  float x  = TAB_L0 + (float)j / INV_H;
  gtab[j] = eval_exact(x, vt, at) * sc;
}

__device__ __forceinline__ void nt_store4(float4 o, float4* p) {
  nfloat4 v = {o.x, o.y, o.z, o.w};
  __builtin_nontemporal_store(v, (nfloat4*)p);
}

// Per-element lerp from the bank-private replicated table.
// Index clamp WITHOUT clamping u -> linear extrapolation, exact in the affine tails.
__device__ __forceinline__ float lerp_tab(float x, float C1, float C0, int lrep,
                                          const float* __restrict__ vrep) {
  float s  = fmaf(x, C1, C0);
  float fj = fminf(fmaxf(floorf(s), 0.0f), (float)(TAB_K - 2));
  float u  = s - fj;                       // may be <0 or >1: extrapolation
  int   off = ((int)fj << 4) | lrep;       // replica l&15: <=2 lanes/bank/phase
  float a0 = vrep[off];
  float a1 = vrep[off + REP];
  return fmaf(u, a1 - a0, a0);
}

// Main kernel: 8 float4 loads issued back-to-back, then 32 conflict-free LDS
// lookups, then 8 nontemporal float4 stores.
__global__ __launch_bounds__(BLK, 4) void apply_map_kernel(
    const float4* __restrict__ in, float4* __restrict__ out,
    const float* __restrict__ gtab, const float* __restrict__ ctp, int nf4) {
  __shared__ float vrep[TAB_K * REP];      // 512*16*4 = 32 KiB -> 5 blocks/CU
  {
    // addr = tid + k*256 -> bank = tid%32: conflict-free writes.
#pragma unroll
    for (int k = 0; k < (TAB_K * REP) / BLK; ++k) {
      int i = (int)threadIdx.x + k * BLK;
      vrep[i] = gtab[i >> 4];              // 4 distinct words per wave-load
    }
  }
  float C1 = ctp[0] * (MAXVAL_F * INV_H);  // s = data*C1 + C0
  const float C0 = -TAB_L0 * INV_H;
  int lrep = (int)threadIdx.x & (REP - 1);
  __syncthreads();

  int base = (int)blockIdx.x * F4_PER_BLOCK + (int)threadIdx.x;

  if (base + (ITER - 1) * BLK < nf4) {     // full block: unchecked fast path
    float4 d[ITER];
#pragma unroll
    for (int k = 0; k < ITER; ++k) d[k] = in[base + k * BLK];
#pragma unroll
    for (int k = 0; k < ITER; ++k) {
      float4 o;
      o.x = lerp_tab(d[k].x, C1, C0, lrep, vrep);
      o.y = lerp_tab(d[k].y, C1, C0, lrep, vrep);
      o.z = lerp_tab(d[k].z, C1, C0, lrep, vrep);
      o.w = lerp_tab(d[k].w, C1, C0, lrep, vrep);
      nt_store4(o, &out[base + k * BLK]);
    }
  } else {                                  // ragged tail (unused at N=2^25)
#pragma unroll
    for (int k = 0; k < ITER; ++k) {
      int idx = base + k * BLK;
      if (idx < nf4) {
        float4 d = in[idx];
        float4 o;
        o.x = lerp_tab(d.x, C1, C0, lrep, vrep);
        o.y = lerp_tab(d.y, C1, C0, lrep, vrep);
        o.z = lerp_tab(d.z, C1, C0, lrep, vrep);
        o.w = lerp_tab(d.w, C1, C0, lrep, vrep);
        nt_store4(o, &out[idx]);
      }
    }
  }
}

extern "C" void kernel_launch(void* const* d_in, const int* in_sizes, int n_in,
                              void* d_out, int out_size, void* d_ws, size_t ws_size,
                              hipStream_t stream) {
  const float* data = (const float*)d_in[0];
  const float* vel  = (const float*)d_in[1];
  const float* ang  = (const float*)d_in[2];
  const float* ct   = (const float*)d_in[3];
  const float* st   = (const float*)d_in[4];
  float*       outp = (float*)d_out;
  float*       gtab = (float*)d_ws;   // 512 * 4 B = 2 KiB scratch

  hipLaunchKernelGGL(build_table_kernel, dim3((TAB_K + 255) / 256), dim3(256), 0, stream,
                     vel, ang, st, gtab);

  int n   = in_sizes[0];          // 33,554,432
  int nf4 = n / 4;                // 8,388,608 = 4096 * 2048 exactly
  int blocks = (nf4 + F4_PER_BLOCK - 1) / F4_PER_BLOCK;
  hipLaunchKernelGGL(apply_map_kernel, dim3(blocks), dim3(BLK), 0, stream,
                     (const float4*)data, (float4*)outp, gtab, ct, nf4);
}